// Round 7
// baseline (58.790 us; speedup 1.0000x reference)
//
#include <hip/hip_runtime.h>

#define CC 16
#define OO 32
#define LL 65536   // 256*256

typedef __attribute__((ext_vector_type(8))) short bf16x8;
typedef __attribute__((ext_vector_type(4))) float f32x4;
typedef __attribute__((ext_vector_type(4))) int   i32x4;

static __device__ __forceinline__ ushort f2b(float f) {   // exact RNE (prepass)
    union { float f; unsigned u; } v; v.f = f;
    return (ushort)((v.u + 0x7fff + ((v.u >> 16) & 1)) >> 16);
}
// pack two floats -> (bf16(fh)<<16)|bf16(fl), round-half-up: proven R2-R4/R6
static __device__ __forceinline__ unsigned pk2(float fl, float fh) {
    unsigned ul = __float_as_uint(fl) + 0x8000u;
    unsigned uh = __float_as_uint(fh) + 0x8000u;
    return __builtin_amdgcn_perm(uh, ul, 0x07060302);
}
static __device__ __forceinline__ float tanh_fast(float x) {
    float e = __expf(2.f * x);
    return 1.f - 2.f / (e + 1.f);
}

// ---- prepass: weights -> bf16 in exact MFMA A-fragment order (unchanged) ----
__global__ void prepass(const float* __restrict__ W1, const float* __restrict__ b1,
                        const float* __restrict__ W2, const float* __restrict__ b2,
                        const float* __restrict__ bias,
                        ushort* __restrict__ w1f, ushort* __restrict__ w2f) {
    int idx = blockIdx.x * 256 + threadIdx.x;
    if (idx < 5120) {
        int f = idx >> 9, lane = (idx >> 3) & 63, j = idx & 7;
        int ks = f >> 1, ot = f & 1, lm = lane & 15, g = lane >> 4;
        int o = ot * 16 + lm, kk = ks * 32 + g * 8 + j;
        int r = kk >> 4, c = kk & 15;
        float v = (kk < 144) ? W1[o * 144 + c * 9 + r] : (kk == 144 ? b1[o] : 0.f);
        w1f[idx] = f2b(v);
    } else if (idx < 15360) {
        int i2 = idx - 5120;
        int f = i2 >> 9, lane = (i2 >> 3) & 63, j = i2 & 7;
        int ks = f >> 1, ot = f & 1, lm = lane & 15, g = lane >> 4;
        int o = ot * 16 + lm, kk = ks * 32 + g * 8 + j;
        float v;
        if      (kk < 288) v = W2[o * 288 + kk];
        else if (kk < 297) v = b2[o * 9 + (kk - 288)];
        else if (kk == 297) v = bias[o];
        else               v = 0.f;
        w2f[i2] = f2b(v);
    }
}

// ---- main: 512 thr (8 waves), 2 compute rows/block, grid 512; W1 regs, W2 LDS ----
__global__ __launch_bounds__(512, 4) void dynaconv_mfma(
    const float* __restrict__ x, const ushort* __restrict__ w1f,
    const ushort* __restrict__ w2f, float* __restrict__ out)
{
    __shared__ __align__(16) ushort xs[4][258][16];   // 33,024 B: rows h0-1..h0+2, bf16
    __shared__ __align__(16) float  S[4][258];        //  4,128 B: channel sums
    __shared__ __align__(16) ushort extb[16];         //     32 B: phase-1 K-ext pattern
    __shared__ __align__(16) ushort W2L[20 * 512];    // 20,480 B: W2 frags (f*512+lane*8)

    const int tid  = threadIdx.x;
    const int wv   = tid >> 6;
    const int lane = tid & 63;
    const int g    = lane >> 4;
    const int lm   = lane & 15;

    // XCD-chunked swizzle (512 = 8*64, bijective)
    const int vbid = (blockIdx.x & 7) * 64 + (blockIdx.x >> 3);
    const int b    = vbid >> 7;
    const int h0   = (vbid & 127) * 2;

    // ---- W1 fragments -> regs (40 VGPR) ----
    bf16x8 W1R[10];
#pragma unroll
    for (int f = 0; f < 10; ++f) W1R[f] = *(const bf16x8*)(w1f + (f * 64 + lane) * 8);

    // ---- W2 fragments -> LDS (1280 x 16B linear) ----
    {
        const i32x4* src = (const i32x4*)w2f;
        i32x4*       dst = (i32x4*)W2L;
#pragma unroll
        for (int k = 0; k < 3; ++k) {
            int i = tid + k * 512;
            if (i < 1280) dst[i] = src[i];
        }
    }

    // ---- stage 4 rows x 256 cols x 16 ch -> bf16 LDS + fp32 channel sums ----
    const float* xb = x + b * (CC * LL);
    {
        const int col = tid & 255;
        const int rp  = tid >> 8;            // 0: rows {h0-1,h0}; 1: rows {h0+1,h0+2}
        const int ra  = rp * 2;              // xs row index a
        const int ha  = h0 - 1 + ra;
        const int hbb = ha + 1;
        const bool oka = (unsigned)ha  < 256u;
        const bool okb = (unsigned)hbb < 256u;
        const int offa = (oka ? ha  : 0) * 256 + col;
        const int offb = (okb ? hbb : 0) * 256 + col;
        float sa = 0.f, sb = 0.f;
#pragma unroll
        for (int cp = 0; cp < 8; ++cp) {
            const float* p0 = xb + (2 * cp) * LL;
            const float* p1 = p0 + LL;
            float va0 = p0[offa], vb0 = p1[offa];
            float va1 = p0[offb], vb1 = p1[offb];
            va0 = oka ? va0 : 0.f; vb0 = oka ? vb0 : 0.f;
            va1 = okb ? va1 : 0.f; vb1 = okb ? vb1 : 0.f;
            sa += va0 + vb0; sb += va1 + vb1;
            *(unsigned*)&xs[ra][col + 1][2 * cp]     = pk2(va0, vb0);
            *(unsigned*)&xs[ra + 1][col + 1][2 * cp] = pk2(va1, vb1);
        }
        S[ra][col + 1] = sa; S[ra + 1][col + 1] = sb;
    }
    if (tid < 64) { int r = tid >> 4, side = (tid >> 3) & 1, cw = tid & 7;
                    *(unsigned*)&xs[r][side * 257][2 * cw] = 0u; }
    if (tid < 8)  S[tid >> 1][(tid & 1) * 257] = 0.f;
    if (tid < 16) extb[tid] = (tid == 0) ? (ushort)0x3F80 : (ushort)0;
    __syncthreads();   // the only barrier

    // per-ks feat LDS offsets (ushort units, hr/tile-independent part)
    int soff[5];
#pragma unroll
    for (int ks = 0; ks < 5; ++ks) {
        int r = 2 * ks + (g >> 1); if (r > 8) r = 8;
        int r3 = (r * 11) >> 5, rm = r - 3 * r3;
        soff[ks] = (r3 * 258 + rm + lm) * 16 + (g & 1) * 8;
    }
    const ushort* xsf = &xs[0][0][0];
    const ushort* w2b = W2L + lane * 8;
    const int sA = ((g & 1) << 5) | lm;   // hid shuffle sources
    const int sB = sA + 16;
    const int hh = g >> 1;

    const int hr = wv >> 2;               // compute row 0/1 for this wave
    const int q  = wv & 3;                // pixel quarter

#pragma unroll 1
    for (int p = 0; p < 2; ++p) {
        const int w0A = q * 64 + p * 32;
        const int w0B = w0A + 16;
        const int tbA = (hr * 258 + w0A) * 16;
        const int tbB = tbA + 256;
        const ushort* p4A = (g < 2) ? (xsf + soff[4] + tbA) : (extb + (g - 2) * 8);
        const ushort* p4B = (g < 2) ? (xsf + soff[4] + tbB) : (extb + (g - 2) * 8);

        // ---- phase 1 (pair-interleaved): hid[o,pix] = W1e @ feat ----
        f32x4 a1A0 = {0,0,0,0}, a1A1 = {0,0,0,0}, a1B0 = {0,0,0,0}, a1B1 = {0,0,0,0};
#pragma unroll
        for (int ks = 0; ks < 4; ++ks) {
            bf16x8 fA = *(const bf16x8*)(xsf + soff[ks] + tbA);
            bf16x8 fB = *(const bf16x8*)(xsf + soff[ks] + tbB);
            a1A0 = __builtin_amdgcn_mfma_f32_16x16x32_bf16(W1R[2 * ks],     fA, a1A0, 0, 0, 0);
            a1A1 = __builtin_amdgcn_mfma_f32_16x16x32_bf16(W1R[2 * ks + 1], fA, a1A1, 0, 0, 0);
            a1B0 = __builtin_amdgcn_mfma_f32_16x16x32_bf16(W1R[2 * ks],     fB, a1B0, 0, 0, 0);
            a1B1 = __builtin_amdgcn_mfma_f32_16x16x32_bf16(W1R[2 * ks + 1], fB, a1B1, 0, 0, 0);
        }
        {
            bf16x8 fA = *(const bf16x8*)p4A;
            bf16x8 fB = *(const bf16x8*)p4B;
            a1A0 = __builtin_amdgcn_mfma_f32_16x16x32_bf16(W1R[8], fA, a1A0, 0, 0, 0);
            a1A1 = __builtin_amdgcn_mfma_f32_16x16x32_bf16(W1R[9], fA, a1A1, 0, 0, 0);
            a1B0 = __builtin_amdgcn_mfma_f32_16x16x32_bf16(W1R[8], fB, a1B0, 0, 0, 0);
            a1B1 = __builtin_amdgcn_mfma_f32_16x16x32_bf16(W1R[9], fB, a1B1, 0, 0, 0);
        }

        // ---- tanh -> packed words -> shuffle redistribute (proven R6 pattern) ----
        unsigned WqA[4], WqB[4];
#pragma unroll
        for (int qq = 0; qq < 4; ++qq) {
            WqA[qq] = pk2(tanh_fast(a1A0[qq]), tanh_fast(a1A1[qq]));
            WqB[qq] = pk2(tanh_fast(a1B0[qq]), tanh_fast(a1B1[qq]));
        }
        float hfA[8], hfB[8];
#pragma unroll
        for (int qq = 0; qq < 4; ++qq) {
            unsigned pa = (unsigned)__shfl((int)WqA[qq], sA);
            unsigned pb = (unsigned)__shfl((int)WqA[qq], sB);
            hfA[qq]     = __uint_as_float(hh ? (pa & 0xffff0000u) : (pa << 16));
            hfA[4 + qq] = __uint_as_float(hh ? (pb & 0xffff0000u) : (pb << 16));
            unsigned pc_ = (unsigned)__shfl((int)WqB[qq], sA);
            unsigned pd  = (unsigned)__shfl((int)WqB[qq], sB);
            hfB[qq]     = __uint_as_float(hh ? (pc_ & 0xffff0000u) : (pc_ << 16));
            hfB[4 + qq] = __uint_as_float(hh ? (pd & 0xffff0000u) : (pd << 16));
        }

        float pcA[9], pcB[9];
#pragma unroll
        for (int r = 0; r < 9; ++r) {
            pcA[r] = S[r / 3 + hr][w0A + lm + (r % 3)];
            pcB[r] = S[r / 3 + hr][w0B + lm + (r % 3)];
        }

        // ---- phase 2 (W2 frag shared across the tile pair) ----
        f32x4 a2A0 = {0,0,0,0}, a2A1 = {0,0,0,0}, a2B0 = {0,0,0,0}, a2B1 = {0,0,0,0};
#pragma unroll
        for (int ks = 0; ks < 9; ++ks) {
            bf16x8 bm0 = *(const bf16x8*)(w2b + (2 * ks) * 512);
            bf16x8 bm1 = *(const bf16x8*)(w2b + (2 * ks + 1) * 512);
            const float pA = pcA[ks], pB = pcB[ks];
            i32x4 wA, wB;
            wA[0] = (int)pk2(hfA[0] * pA, hfA[1] * pA);
            wA[1] = (int)pk2(hfA[2] * pA, hfA[3] * pA);
            wA[2] = (int)pk2(hfA[4] * pA, hfA[5] * pA);
            wA[3] = (int)pk2(hfA[6] * pA, hfA[7] * pA);
            wB[0] = (int)pk2(hfB[0] * pB, hfB[1] * pB);
            wB[1] = (int)pk2(hfB[2] * pB, hfB[3] * pB);
            wB[2] = (int)pk2(hfB[4] * pB, hfB[5] * pB);
            wB[3] = (int)pk2(hfB[6] * pB, hfB[7] * pB);
            bf16x8 fA = *(bf16x8*)&wA;
            bf16x8 fB = *(bf16x8*)&wB;
            a2A0 = __builtin_amdgcn_mfma_f32_16x16x32_bf16(bm0, fA, a2A0, 0, 0, 0);
            a2A1 = __builtin_amdgcn_mfma_f32_16x16x32_bf16(bm1, fA, a2A1, 0, 0, 0);
            a2B0 = __builtin_amdgcn_mfma_f32_16x16x32_bf16(bm0, fB, a2B0, 0, 0, 0);
            a2B1 = __builtin_amdgcn_mfma_f32_16x16x32_bf16(bm1, fB, a2B1, 0, 0, 0);
        }
        {   // ks==9 K-extension (b2*pc + bias)
            bf16x8 bm0 = *(const bf16x8*)(w2b + 18 * 512);
            bf16x8 bm1 = *(const bf16x8*)(w2b + 19 * 512);
            i32x4 wA, wB;
            wA[0] = (g == 0) ? (int)pk2(pcA[0], pcA[1]) : ((g == 1) ? (int)pk2(pcA[8], 1.f) : 0);
            wA[1] = (g == 0) ? (int)pk2(pcA[2], pcA[3]) : 0;
            wA[2] = (g == 0) ? (int)pk2(pcA[4], pcA[5]) : 0;
            wA[3] = (g == 0) ? (int)pk2(pcA[6], pcA[7]) : 0;
            wB[0] = (g == 0) ? (int)pk2(pcB[0], pcB[1]) : ((g == 1) ? (int)pk2(pcB[8], 1.f) : 0);
            wB[1] = (g == 0) ? (int)pk2(pcB[2], pcB[3]) : 0;
            wB[2] = (g == 0) ? (int)pk2(pcB[4], pcB[5]) : 0;
            wB[3] = (g == 0) ? (int)pk2(pcB[6], pcB[7]) : 0;
            bf16x8 fA = *(bf16x8*)&wA;
            bf16x8 fB = *(bf16x8*)&wB;
            a2A0 = __builtin_amdgcn_mfma_f32_16x16x32_bf16(bm0, fA, a2A0, 0, 0, 0);
            a2A1 = __builtin_amdgcn_mfma_f32_16x16x32_bf16(bm1, fA, a2A1, 0, 0, 0);
            a2B0 = __builtin_amdgcn_mfma_f32_16x16x32_bf16(bm0, fB, a2B0, 0, 0, 0);
            a2B1 = __builtin_amdgcn_mfma_f32_16x16x32_bf16(bm1, fB, a2B1, 0, 0, 0);
        }

        // ---- stores straight from accumulators ----
        float* obA = out + b * (OO * LL) + (h0 + hr) * 256 + w0A + lm;
        float* obB = obA + 16;
#pragma unroll
        for (int qq = 0; qq < 4; ++qq) {
            obA[(g * 4 + qq) * LL]        = a2A0[qq];
            obA[(16 + g * 4 + qq) * LL]   = a2A1[qq];
            obB[(g * 4 + qq) * LL]        = a2B0[qq];
            obB[(16 + g * 4 + qq) * LL]   = a2B1[qq];
        }
    }
}

extern "C" void kernel_launch(void* const* d_in, const int* in_sizes, int n_in,
                              void* d_out, int out_size, void* d_ws, size_t ws_size,
                              hipStream_t stream) {
    const float* x    = (const float*)d_in[0];
    const float* W1   = (const float*)d_in[1];
    const float* b1   = (const float*)d_in[2];
    const float* W2   = (const float*)d_in[3];
    const float* b2   = (const float*)d_in[4];
    const float* bias = (const float*)d_in[5];
    float* out = (float*)d_out;

    ushort* w1f = (ushort*)d_ws;        // 5120 bf16
    ushort* w2f = w1f + 5120;           // 10240 bf16

    prepass<<<60, 256, 0, stream>>>(W1, b1, W2, b2, bias, w1f, w2f);
    dynaconv_mfma<<<512, 512, 0, stream>>>(x, w1f, w2f, out);
}

// Round 8
// 32.676 us; speedup vs baseline: 1.7992x; 1.7992x over previous
//
#include <hip/hip_runtime.h>

#define CC 16
#define OO 32
#define LL 65536   // 256*256

typedef __attribute__((ext_vector_type(8))) short bf16x8;
typedef __attribute__((ext_vector_type(4))) float f32x4;
typedef __attribute__((ext_vector_type(4))) int   i32x4;

static __device__ __forceinline__ ushort f2b(float f) {   // exact RNE (prepass)
    union { float f; unsigned u; } v; v.f = f;
    return (ushort)((v.u + 0x7fff + ((v.u >> 16) & 1)) >> 16);
}
// pack two floats -> (bf16(fh)<<16)|bf16(fl), round-half-up: proven R2-R4/R6/R7
static __device__ __forceinline__ unsigned pk2(float fl, float fh) {
    unsigned ul = __float_as_uint(fl) + 0x8000u;
    unsigned uh = __float_as_uint(fh) + 0x8000u;
    return __builtin_amdgcn_perm(uh, ul, 0x07060302);
}
static __device__ __forceinline__ float tanh_fast(float x) {
    float e = __expf(2.f * x);
    return 1.f - 2.f / (e + 1.f);
}

// ---- prepass: weights -> bf16 in exact MFMA A-fragment order (unchanged) ----
__global__ void prepass(const float* __restrict__ W1, const float* __restrict__ b1,
                        const float* __restrict__ W2, const float* __restrict__ b2,
                        const float* __restrict__ bias,
                        ushort* __restrict__ w1f, ushort* __restrict__ w2f) {
    int idx = blockIdx.x * 256 + threadIdx.x;
    if (idx < 5120) {
        int f = idx >> 9, lane = (idx >> 3) & 63, j = idx & 7;
        int ks = f >> 1, ot = f & 1, lm = lane & 15, g = lane >> 4;
        int o = ot * 16 + lm, kk = ks * 32 + g * 8 + j;
        int r = kk >> 4, c = kk & 15;
        float v = (kk < 144) ? W1[o * 144 + c * 9 + r] : (kk == 144 ? b1[o] : 0.f);
        w1f[idx] = f2b(v);
    } else if (idx < 15360) {
        int i2 = idx - 5120;
        int f = i2 >> 9, lane = (i2 >> 3) & 63, j = i2 & 7;
        int ks = f >> 1, ot = f & 1, lm = lane & 15, g = lane >> 4;
        int o = ot * 16 + lm, kk = ks * 32 + g * 8 + j;
        float v;
        if      (kk < 288) v = W2[o * 288 + kk];
        else if (kk < 297) v = b2[o * 9 + (kk - 288)];
        else if (kk == 297) v = bias[o];
        else               v = 0.f;
        w2f[i2] = f2b(v);
    }
}

// ---- main: 512 thr (8 waves), 2 compute rows/block, grid 512; W1 regs, W2 LDS ----
// __launch_bounds__ 2nd arg behaves as min BLOCKS/CU (empirical R6/R7: (512,4)->64-reg cap
// with spills; (256,2)->~228 regs). (512,2) -> 128-reg cap, 2 blocks/CU = 4 waves/SIMD.
__global__ __launch_bounds__(512, 2) void dynaconv_mfma(
    const float* __restrict__ x, const ushort* __restrict__ w1f,
    const ushort* __restrict__ w2f, float* __restrict__ out)
{
    __shared__ __align__(16) ushort xs[4][258][16];   // 33,024 B: rows h0-1..h0+2, bf16
    __shared__ __align__(16) float  S[4][258];        //  4,128 B: channel sums
    __shared__ __align__(16) ushort extb[16];         //     32 B: phase-1 K-ext pattern
    __shared__ __align__(16) ushort W2L[20 * 512];    // 20,480 B: W2 frags (f*512+lane*8)

    const int tid  = threadIdx.x;
    const int wv   = tid >> 6;
    const int lane = tid & 63;
    const int g    = lane >> 4;
    const int lm   = lane & 15;

    // XCD-chunked swizzle (512 = 8*64, bijective)
    const int vbid = (blockIdx.x & 7) * 64 + (blockIdx.x >> 3);
    const int b    = vbid >> 7;
    const int h0   = (vbid & 127) * 2;

    // ---- W1 fragments -> regs (40 VGPR) ----
    bf16x8 W1R[10];
#pragma unroll
    for (int f = 0; f < 10; ++f) W1R[f] = *(const bf16x8*)(w1f + (f * 64 + lane) * 8);

    // ---- W2 fragments -> LDS (1280 x 16B linear) ----
    {
        const i32x4* src = (const i32x4*)w2f;
        i32x4*       dst = (i32x4*)W2L;
#pragma unroll
        for (int k = 0; k < 3; ++k) {
            int i = tid + k * 512;
            if (i < 1280) dst[i] = src[i];
        }
    }

    // ---- stage 4 rows x 256 cols x 16 ch -> bf16 LDS + fp32 channel sums ----
    const float* xb = x + b * (CC * LL);
    {
        const int col = tid & 255;
        const int rp  = tid >> 8;            // 0: rows {h0-1,h0}; 1: rows {h0+1,h0+2}
        const int ra  = rp * 2;              // xs row index a
        const int ha  = h0 - 1 + ra;
        const int hbb = ha + 1;
        const bool oka = (unsigned)ha  < 256u;
        const bool okb = (unsigned)hbb < 256u;
        const int offa = (oka ? ha  : 0) * 256 + col;
        const int offb = (okb ? hbb : 0) * 256 + col;
        float sa = 0.f, sb = 0.f;
#pragma unroll
        for (int cp = 0; cp < 8; ++cp) {
            const float* p0 = xb + (2 * cp) * LL;
            const float* p1 = p0 + LL;
            float va0 = p0[offa], vb0 = p1[offa];
            float va1 = p0[offb], vb1 = p1[offb];
            va0 = oka ? va0 : 0.f; vb0 = oka ? vb0 : 0.f;
            va1 = okb ? va1 : 0.f; vb1 = okb ? vb1 : 0.f;
            sa += va0 + vb0; sb += va1 + vb1;
            *(unsigned*)&xs[ra][col + 1][2 * cp]     = pk2(va0, vb0);
            *(unsigned*)&xs[ra + 1][col + 1][2 * cp] = pk2(va1, vb1);
        }
        S[ra][col + 1] = sa; S[ra + 1][col + 1] = sb;
    }
    if (tid < 64) { int r = tid >> 4, side = (tid >> 3) & 1, cw = tid & 7;
                    *(unsigned*)&xs[r][side * 257][2 * cw] = 0u; }
    if (tid < 8)  S[tid >> 1][(tid & 1) * 257] = 0.f;
    if (tid < 16) extb[tid] = (tid == 0) ? (ushort)0x3F80 : (ushort)0;
    __syncthreads();   // the only barrier

    // per-ks feat LDS offsets (ushort units, hr/tile-independent part)
    int soff[5];
#pragma unroll
    for (int ks = 0; ks < 5; ++ks) {
        int r = 2 * ks + (g >> 1); if (r > 8) r = 8;
        int r3 = (r * 11) >> 5, rm = r - 3 * r3;
        soff[ks] = (r3 * 258 + rm + lm) * 16 + (g & 1) * 8;
    }
    const ushort* xsf = &xs[0][0][0];
    const ushort* w2b = W2L + lane * 8;
    const int sA = ((g & 1) << 5) | lm;   // hid shuffle sources
    const int sB = sA + 16;
    const int hh = g >> 1;

    const int hr = wv >> 2;               // compute row 0/1 for this wave
    const int q  = wv & 3;                // pixel quarter

#pragma unroll 1
    for (int p = 0; p < 2; ++p) {
        const int w0A = q * 64 + p * 32;
        const int w0B = w0A + 16;
        const int tbA = (hr * 258 + w0A) * 16;
        const int tbB = tbA + 256;
        const ushort* p4A = (g < 2) ? (xsf + soff[4] + tbA) : (extb + (g - 2) * 8);
        const ushort* p4B = (g < 2) ? (xsf + soff[4] + tbB) : (extb + (g - 2) * 8);

        // ---- phase 1 (pair-interleaved): hid[o,pix] = W1e @ feat ----
        f32x4 a1A0 = {0,0,0,0}, a1A1 = {0,0,0,0}, a1B0 = {0,0,0,0}, a1B1 = {0,0,0,0};
#pragma unroll
        for (int ks = 0; ks < 4; ++ks) {
            bf16x8 fA = *(const bf16x8*)(xsf + soff[ks] + tbA);
            bf16x8 fB = *(const bf16x8*)(xsf + soff[ks] + tbB);
            a1A0 = __builtin_amdgcn_mfma_f32_16x16x32_bf16(W1R[2 * ks],     fA, a1A0, 0, 0, 0);
            a1A1 = __builtin_amdgcn_mfma_f32_16x16x32_bf16(W1R[2 * ks + 1], fA, a1A1, 0, 0, 0);
            a1B0 = __builtin_amdgcn_mfma_f32_16x16x32_bf16(W1R[2 * ks],     fB, a1B0, 0, 0, 0);
            a1B1 = __builtin_amdgcn_mfma_f32_16x16x32_bf16(W1R[2 * ks + 1], fB, a1B1, 0, 0, 0);
        }
        {
            bf16x8 fA = *(const bf16x8*)p4A;
            bf16x8 fB = *(const bf16x8*)p4B;
            a1A0 = __builtin_amdgcn_mfma_f32_16x16x32_bf16(W1R[8], fA, a1A0, 0, 0, 0);
            a1A1 = __builtin_amdgcn_mfma_f32_16x16x32_bf16(W1R[9], fA, a1A1, 0, 0, 0);
            a1B0 = __builtin_amdgcn_mfma_f32_16x16x32_bf16(W1R[8], fB, a1B0, 0, 0, 0);
            a1B1 = __builtin_amdgcn_mfma_f32_16x16x32_bf16(W1R[9], fB, a1B1, 0, 0, 0);
        }

        // ---- tanh -> packed words -> shuffle redistribute (proven R6 pattern) ----
        unsigned WqA[4], WqB[4];
#pragma unroll
        for (int qq = 0; qq < 4; ++qq) {
            WqA[qq] = pk2(tanh_fast(a1A0[qq]), tanh_fast(a1A1[qq]));
            WqB[qq] = pk2(tanh_fast(a1B0[qq]), tanh_fast(a1B1[qq]));
        }
        float hfA[8], hfB[8];
#pragma unroll
        for (int qq = 0; qq < 4; ++qq) {
            unsigned pa = (unsigned)__shfl((int)WqA[qq], sA);
            unsigned pb = (unsigned)__shfl((int)WqA[qq], sB);
            hfA[qq]     = __uint_as_float(hh ? (pa & 0xffff0000u) : (pa << 16));
            hfA[4 + qq] = __uint_as_float(hh ? (pb & 0xffff0000u) : (pb << 16));
            unsigned pc_ = (unsigned)__shfl((int)WqB[qq], sA);
            unsigned pd  = (unsigned)__shfl((int)WqB[qq], sB);
            hfB[qq]     = __uint_as_float(hh ? (pc_ & 0xffff0000u) : (pc_ << 16));
            hfB[4 + qq] = __uint_as_float(hh ? (pd & 0xffff0000u) : (pd << 16));
        }

        float pcA[9], pcB[9];
#pragma unroll
        for (int r = 0; r < 9; ++r) {
            pcA[r] = S[r / 3 + hr][w0A + lm + (r % 3)];
            pcB[r] = S[r / 3 + hr][w0B + lm + (r % 3)];
        }

        // ---- phase 2 (W2 frag shared across the tile pair) ----
        f32x4 a2A0 = {0,0,0,0}, a2A1 = {0,0,0,0}, a2B0 = {0,0,0,0}, a2B1 = {0,0,0,0};
#pragma unroll
        for (int ks = 0; ks < 9; ++ks) {
            bf16x8 bm0 = *(const bf16x8*)(w2b + (2 * ks) * 512);
            bf16x8 bm1 = *(const bf16x8*)(w2b + (2 * ks + 1) * 512);
            const float pA = pcA[ks], pB = pcB[ks];
            i32x4 wA, wB;
            wA[0] = (int)pk2(hfA[0] * pA, hfA[1] * pA);
            wA[1] = (int)pk2(hfA[2] * pA, hfA[3] * pA);
            wA[2] = (int)pk2(hfA[4] * pA, hfA[5] * pA);
            wA[3] = (int)pk2(hfA[6] * pA, hfA[7] * pA);
            wB[0] = (int)pk2(hfB[0] * pB, hfB[1] * pB);
            wB[1] = (int)pk2(hfB[2] * pB, hfB[3] * pB);
            wB[2] = (int)pk2(hfB[4] * pB, hfB[5] * pB);
            wB[3] = (int)pk2(hfB[6] * pB, hfB[7] * pB);
            bf16x8 fA = *(bf16x8*)&wA;
            bf16x8 fB = *(bf16x8*)&wB;
            a2A0 = __builtin_amdgcn_mfma_f32_16x16x32_bf16(bm0, fA, a2A0, 0, 0, 0);
            a2A1 = __builtin_amdgcn_mfma_f32_16x16x32_bf16(bm1, fA, a2A1, 0, 0, 0);
            a2B0 = __builtin_amdgcn_mfma_f32_16x16x32_bf16(bm0, fB, a2B0, 0, 0, 0);
            a2B1 = __builtin_amdgcn_mfma_f32_16x16x32_bf16(bm1, fB, a2B1, 0, 0, 0);
        }
        {   // ks==9 K-extension (b2*pc + bias)
            bf16x8 bm0 = *(const bf16x8*)(w2b + 18 * 512);
            bf16x8 bm1 = *(const bf16x8*)(w2b + 19 * 512);
            i32x4 wA, wB;
            wA[0] = (g == 0) ? (int)pk2(pcA[0], pcA[1]) : ((g == 1) ? (int)pk2(pcA[8], 1.f) : 0);
            wA[1] = (g == 0) ? (int)pk2(pcA[2], pcA[3]) : 0;
            wA[2] = (g == 0) ? (int)pk2(pcA[4], pcA[5]) : 0;
            wA[3] = (g == 0) ? (int)pk2(pcA[6], pcA[7]) : 0;
            wB[0] = (g == 0) ? (int)pk2(pcB[0], pcB[1]) : ((g == 1) ? (int)pk2(pcB[8], 1.f) : 0);
            wB[1] = (g == 0) ? (int)pk2(pcB[2], pcB[3]) : 0;
            wB[2] = (g == 0) ? (int)pk2(pcB[4], pcB[5]) : 0;
            wB[3] = (g == 0) ? (int)pk2(pcB[6], pcB[7]) : 0;
            bf16x8 fA = *(bf16x8*)&wA;
            bf16x8 fB = *(bf16x8*)&wB;
            a2A0 = __builtin_amdgcn_mfma_f32_16x16x32_bf16(bm0, fA, a2A0, 0, 0, 0);
            a2A1 = __builtin_amdgcn_mfma_f32_16x16x32_bf16(bm1, fA, a2A1, 0, 0, 0);
            a2B0 = __builtin_amdgcn_mfma_f32_16x16x32_bf16(bm0, fB, a2B0, 0, 0, 0);
            a2B1 = __builtin_amdgcn_mfma_f32_16x16x32_bf16(bm1, fB, a2B1, 0, 0, 0);
        }

        // ---- stores straight from accumulators ----
        float* obA = out + b * (OO * LL) + (h0 + hr) * 256 + w0A + lm;
        float* obB = obA + 16;
#pragma unroll
        for (int qq = 0; qq < 4; ++qq) {
            obA[(g * 4 + qq) * LL]        = a2A0[qq];
            obA[(16 + g * 4 + qq) * LL]   = a2A1[qq];
            obB[(g * 4 + qq) * LL]        = a2B0[qq];
            obB[(16 + g * 4 + qq) * LL]   = a2B1[qq];
        }
    }
}

extern "C" void kernel_launch(void* const* d_in, const int* in_sizes, int n_in,
                              void* d_out, int out_size, void* d_ws, size_t ws_size,
                              hipStream_t stream) {
    const float* x    = (const float*)d_in[0];
    const float* W1   = (const float*)d_in[1];
    const float* b1   = (const float*)d_in[2];
    const float* W2   = (const float*)d_in[3];
    const float* b2   = (const float*)d_in[4];
    const float* bias = (const float*)d_in[5];
    float* out = (float*)d_out;

    ushort* w1f = (ushort*)d_ws;        // 5120 bf16
    ushort* w2f = w1f + 5120;           // 10240 bf16

    prepass<<<60, 256, 0, stream>>>(W1, b1, W2, b2, bias, w1f, w2f);
    dynaconv_mfma<<<512, 512, 0, stream>>>(x, w1f, w2f, out);
}

// Round 9
// 28.008 us; speedup vs baseline: 2.0990x; 1.1667x over previous
//
#include <hip/hip_runtime.h>

#define CC 16
#define OO 32
#define LL 65536   // 256*256

typedef __attribute__((ext_vector_type(8))) short bf16x8;
typedef __attribute__((ext_vector_type(4))) float f32x4;
typedef __attribute__((ext_vector_type(4))) int   i32x4;

static __device__ __forceinline__ ushort f2b(float f) {   // exact RNE (prepass)
    union { float f; unsigned u; } v; v.f = f;
    return (ushort)((v.u + 0x7fff + ((v.u >> 16) & 1)) >> 16);
}
// pack two floats -> (bf16(fh)<<16)|bf16(fl), round-half-up (3 ops) — proven R2-R8
static __device__ __forceinline__ unsigned pk2(float fl, float fh) {
    unsigned ul = __float_as_uint(fl) + 0x8000u;
    unsigned uh = __float_as_uint(fh) + 0x8000u;
    return __builtin_amdgcn_perm(uh, ul, 0x07060302);
}
// truncating pack (1 op): bf16 = top 16 bits. Used ONLY for phase-2 hid*pc products.
static __device__ __forceinline__ unsigned pkt(float fl, float fh) {
    return __builtin_amdgcn_perm(__float_as_uint(fh), __float_as_uint(fl), 0x07060302);
}

// ---- prepass: weights -> bf16 in exact MFMA A-fragment order (unchanged from R3/R4) ----
__global__ void prepass(const float* __restrict__ W1, const float* __restrict__ b1,
                        const float* __restrict__ W2, const float* __restrict__ b2,
                        const float* __restrict__ bias,
                        ushort* __restrict__ w1f, ushort* __restrict__ w2f) {
    int idx = blockIdx.x * 256 + threadIdx.x;
    if (idx < 5120) {
        int f = idx >> 9, lane = (idx >> 3) & 63, j = idx & 7;
        int ks = f >> 1, ot = f & 1, lm = lane & 15, g = lane >> 4;
        int o = ot * 16 + lm, kk = ks * 32 + g * 8 + j;
        int r = kk >> 4, c = kk & 15;
        float v = (kk < 144) ? W1[o * 144 + c * 9 + r] : (kk == 144 ? b1[o] : 0.f);
        w1f[idx] = f2b(v);
    } else if (idx < 15360) {
        int i2 = idx - 5120;
        int f = i2 >> 9, lane = (i2 >> 3) & 63, j = i2 & 7;
        int ks = f >> 1, ot = f & 1, lm = lane & 15, g = lane >> 4;
        int o = ot * 16 + lm, kk = ks * 32 + g * 8 + j;
        float v;
        if      (kk < 288) v = W2[o * 288 + kk];
        else if (kk < 297) v = b2[o * 9 + (kk - 288)];
        else if (kk == 297) v = bias[o];
        else               v = 0.f;
        w2f[i2] = f2b(v);
    }
}

// ---- main: R4 champion structure: 256 thr, 2 rows/block, grid 512, all weights in regs ----
__global__ __launch_bounds__(256, 2) void dynaconv_mfma(
    const float* __restrict__ x, const ushort* __restrict__ w1f,
    const ushort* __restrict__ w2f, float* __restrict__ out)
{
    __shared__ __align__(16) ushort xs[4][260][24];  // bf16 x, rows h0-1..h0+2, halo cols 0/257=0
    __shared__ __align__(16) float  S[4][260];       // fp32 channel sums
    __shared__ __align__(16) float  hidT[4][16][36]; // per-wave hid transpose (wave-private)

    const int tid  = threadIdx.x;
    const int wv   = tid >> 6;
    const int lane = tid & 63;
    const int g    = lane >> 4;
    const int lm   = lane & 15;

    // XCD-chunked swizzle: blocks on one XCD process consecutive row-pairs (L2 reuse)
    const int vbid = (blockIdx.x & 7) * 64 + (blockIdx.x >> 3);   // 512 = 8*64, bijective
    const int b    = vbid >> 7;
    const int h0   = (vbid & 127) * 2;

    // ---- weight fragments -> regs (once per block) ----
    bf16x8 W1R[10], W2R[20];
#pragma unroll
    for (int f = 0; f < 10; ++f) W1R[f] = *(const bf16x8*)(w1f + (f * 64 + lane) * 8);
#pragma unroll
    for (int f = 0; f < 20; ++f) W2R[f] = *(const bf16x8*)(w2f + (f * 64 + lane) * 8);

    // ---- stage 4 rows x 256 cols x 16 ch -> bf16 LDS + fp32 channel sums ----
    const float* xb = x + b * (CC * LL);
    {
        int offr[4]; bool okr[4];
#pragma unroll
        for (int r = 0; r < 4; ++r) {
            const int hh = h0 - 1 + r;
            okr[r] = (unsigned)hh < 256u;
            offr[r] = (okr[r] ? hh : 0) * 256 + tid;
        }
        float sr[4] = {0.f, 0.f, 0.f, 0.f};
#pragma unroll
        for (int cp = 0; cp < 8; ++cp) {
            const float* p0 = xb + (2 * cp) * LL;
            const float* p1 = p0 + LL;
#pragma unroll
            for (int r = 0; r < 4; ++r) {
                float va = p0[offr[r]], vb = p1[offr[r]];
                va = okr[r] ? va : 0.f; vb = okr[r] ? vb : 0.f;
                sr[r] += va + vb;
                *(unsigned*)&xs[r][tid + 1][2 * cp] = pk2(va, vb);
            }
        }
#pragma unroll
        for (int r = 0; r < 4; ++r) S[r][tid + 1] = sr[r];
        if (tid < 128) { int r = tid >> 5, side = (tid >> 4) & 1, c = tid & 15; xs[r][side * 257][c] = 0; }
        if (tid < 8)   S[tid >> 1][(tid & 1) * 257] = 0.f;
    }
    __syncthreads();   // the only barrier

    // per-ks feat LDS offsets (ushort units), loop-invariant
    int soff[5];
#pragma unroll
    for (int ks = 0; ks < 5; ++ks) {
        int r = 2 * ks + (g >> 1); if (r > 8) r = 8;
        int r3 = (r * 11) >> 5, rm = r - 3 * r3;
        soff[ks] = (r3 * 260 + rm + lm) * 24 + (g & 1) * 8;
    }
    const ushort* xsf = &xs[0][0][0];

    for (int hr = 0; hr < 2; ++hr) {
        const int hb = hr * (260 * 24);
#pragma unroll
        for (int t = 0; t < 4; ++t) {
            const int w0t = wv * 64 + t * 16;
            const int tb = w0t * 24 + hb;

            // ---- phase 1: hid[o,pixel] = W1e @ feat ----
            f32x4 a1[2] = {{0.f,0.f,0.f,0.f},{0.f,0.f,0.f,0.f}};
#pragma unroll
            for (int ks = 0; ks < 5; ++ks) {
                bf16x8 ff = *(const bf16x8*)(xsf + soff[ks] + tb);
                if (ks == 4) {               // g>=2: bias-extension K block
                    i32x4 wd = *(i32x4*)&ff;
                    wd[0] = (g < 2) ? wd[0] : (g == 2 ? 0x3F80 : 0);
                    wd[1] = (g < 2) ? wd[1] : 0;
                    wd[2] = (g < 2) ? wd[2] : 0;
                    wd[3] = (g < 2) ? wd[3] : 0;
                    ff = *(bf16x8*)&wd;
                }
                a1[0] = __builtin_amdgcn_mfma_f32_16x16x32_bf16(W1R[2 * ks],     ff, a1[0], 0, 0, 0);
                a1[1] = __builtin_amdgcn_mfma_f32_16x16x32_bf16(W1R[2 * ks + 1], ff, a1[1], 0, 0, 0);
            }

            // ---- tanh -> hidT (wave-private) ----
#pragma unroll
            for (int ot = 0; ot < 2; ++ot)
#pragma unroll
                for (int q = 0; q < 4; ++q) {
                    float e = __expf(2.f * a1[ot][q]);
                    hidT[wv][lm][ot * 16 + g * 4 + q] = 1.f - 2.f / (e + 1.f);
                }
            f32x4 h0v = *(const f32x4*)&hidT[wv][lm][g * 8];
            f32x4 h1v = *(const f32x4*)&hidT[wv][lm][g * 8 + 4];

            float pcv[9];
#pragma unroll
            for (int r = 0; r < 9; ++r) pcv[r] = S[r / 3 + hr][w0t + lm + (r % 3)];

            // ---- phase 2: out[o,pixel] = W2p @ (pc ⊗ hid) — trunc pack (1 op) ----
            f32x4 a2[2] = {{0.f,0.f,0.f,0.f},{0.f,0.f,0.f,0.f}};
#pragma unroll
            for (int ks = 0; ks < 9; ++ks) {
                const float p = pcv[ks];
                i32x4 wd;
                wd[0] = (int)pkt(h0v[0] * p, h0v[1] * p);
                wd[1] = (int)pkt(h0v[2] * p, h0v[3] * p);
                wd[2] = (int)pkt(h1v[0] * p, h1v[1] * p);
                wd[3] = (int)pkt(h1v[2] * p, h1v[3] * p);
                bf16x8 ff2 = *(bf16x8*)&wd;
                a2[0] = __builtin_amdgcn_mfma_f32_16x16x32_bf16(W2R[2 * ks],     ff2, a2[0], 0, 0, 0);
                a2[1] = __builtin_amdgcn_mfma_f32_16x16x32_bf16(W2R[2 * ks + 1], ff2, a2[1], 0, 0, 0);
            }
            {   // ks==9: K-extension block (b2·pc + bias) — keep RNE pack
                i32x4 wd;
                wd[0] = (g == 0) ? (int)pk2(pcv[0], pcv[1]) : ((g == 1) ? (int)pk2(pcv[8], 1.f) : 0);
                wd[1] = (g == 0) ? (int)pk2(pcv[2], pcv[3]) : 0;
                wd[2] = (g == 0) ? (int)pk2(pcv[4], pcv[5]) : 0;
                wd[3] = (g == 0) ? (int)pk2(pcv[6], pcv[7]) : 0;
                bf16x8 ff2 = *(bf16x8*)&wd;
                a2[0] = __builtin_amdgcn_mfma_f32_16x16x32_bf16(W2R[18], ff2, a2[0], 0, 0, 0);
                a2[1] = __builtin_amdgcn_mfma_f32_16x16x32_bf16(W2R[19], ff2, a2[1], 0, 0, 0);
            }

            // ---- plain stores straight from accumulator (nontemporal reverted) ----
            float* ob = out + b * (OO * LL) + (h0 + hr) * 256 + w0t + lm;
#pragma unroll
            for (int ot = 0; ot < 2; ++ot)
#pragma unroll
                for (int q = 0; q < 4; ++q)
                    ob[(ot * 16 + g * 4 + q) * LL] = a2[ot][q];
        }
    }
}

extern "C" void kernel_launch(void* const* d_in, const int* in_sizes, int n_in,
                              void* d_out, int out_size, void* d_ws, size_t ws_size,
                              hipStream_t stream) {
    const float* x    = (const float*)d_in[0];
    const float* W1   = (const float*)d_in[1];
    const float* b1   = (const float*)d_in[2];
    const float* W2   = (const float*)d_in[3];
    const float* b2   = (const float*)d_in[4];
    const float* bias = (const float*)d_in[5];
    float* out = (float*)d_out;

    ushort* w1f = (ushort*)d_ws;        // 5120 bf16
    ushort* w2f = w1f + 5120;           // 10240 bf16

    prepass<<<60, 256, 0, stream>>>(W1, b1, W2, b2, bias, w1f, w2f);
    dynaconv_mfma<<<512, 256, 0, stream>>>(x, w1f, w2f, out);
}